// Round 11
// baseline (9194.476 us; speedup 1.0000x reference)
//
#include <hip/hip_runtime.h>
#include <cmath>

constexpr int NB = 128;     // batch
constexpr int NS = 384;     // seq len
constexpr int NH = 384;     // hidden = input dim

typedef __attribute__((ext_vector_type(2))) float f32x2;
typedef _Float16 h16;
typedef __attribute__((ext_vector_type(4))) _Float16 h16x4;

__device__ __forceinline__ double clampd(double x, double lo, double hi){ return fmin(fmax(x,lo),hi); }
__device__ __forceinline__ double artanh_(double x){ return atanh(clampd(x, -1.0 + 1e-7, 1.0 - 1e-7)); }
__device__ __forceinline__ double normclip(double s){ return sqrt(fmax(s, 1e-15)); }
__device__ __forceinline__ float clampf_(float x, float lo, float hi){ return fminf(fmaxf(x,lo),hi); }
__device__ __forceinline__ float artanhf_(float x){ return atanhf(clampf_(x, -1.f + 1e-7f, 1.f - 1e-7f)); }
__device__ __forceinline__ double wredsumd(double v){
  #pragma unroll
  for (int off = 32; off; off >>= 1) v += __shfl_xor(v, off, 64);
  return v;
}
// norm from a double sum, fp32 result
__device__ __forceinline__ float ncf(double s){ return sqrtf(fmaxf((float)s, 1e-15f)); }

// ---------------- zero ----------------
__global__ void kzerod(double* p, int n){
  int i = blockIdx.x * 256 + threadIdx.x;
  if (i < n) p[i] = 0.0;
}

// ---------------- weight pack (fp8 e4m3, quad-k interleaved, scale x4096 exact) -------------
// Dword dw = column j in row cq; its 4 bytes are c = 4*cq+0..3. 104 rows (96 + 8 pad for
// prefetch over-read). Encode via HW cvt (self-consistent with the decode cvt in krow).
// j<1536: gate W (4 gates x 384); [1536,1920): W_d; [2048,3584) (NW=4096 only): U; else 0.
__global__ void kprepWQ(const float* __restrict__ W_all, const float* __restrict__ W_d,
                        const float* __restrict__ U_all, unsigned* __restrict__ WTQ, int NW)
{
  int i = blockIdx.x * 256 + threadIdx.x;
  int total = 104 * NW;
  if (i >= total) return;
  int cq = i / NW, j = i - cq * NW;
  float v[4];
  #pragma unroll
  for (int p = 0; p < 4; ++p){
    int c = 4 * cq + p;
    float w = 0.f;
    if (c < 384){
      if (j < 1536){ int g = j / 384, r = j % 384; w = W_all[r * 1536 + g * 384 + c]; }
      else if (j < 1920){ int r = j - 1536; w = W_d[r * 384 + c]; }
      else if (NW == 4096 && j >= 2048 && j < 3584){
        int jg = j - 2048; int g = jg / 384, r = jg % 384; w = U_all[(g * 384 + r) * 384 + c];
      }
    }
    v[p] = w * 4096.f;
  }
  int u = __builtin_amdgcn_cvt_pk_fp8_f32(v[0], v[1], 0, false);
  u = __builtin_amdgcn_cvt_pk_fp8_f32(v[2], v[3], u, true);
  WTQ[i] = (unsigned)u;
}

// UT[c][jj] = U_g[r][c], stride 1536 (for the Qp precompute GEMM)
__global__ void kprepU(const float* __restrict__ U_all, float* __restrict__ UT)
{
  int i = blockIdx.x * 256 + threadIdx.x;
  if (i >= 384 * 1536) return;
  int c = i / 1536, jj = i % 1536;
  int g = jj / 384, r = jj % 384;
  UT[i] = U_all[(g * 384 + r) * 384 + c];
}

// ---------------- per-(b,t) scalar precompute (double math, fp32 storage) ----------------
// XNF[idx] = {xn, artanh(xn), artanh(xnt)/xnt, ts}
__global__ void kxn(const float* __restrict__ xin, const float* __restrict__ tst,
                    float* __restrict__ XNF)
{
  int w = (blockIdx.x * 256 + threadIdx.x) >> 6;
  int ln = threadIdx.x & 63;
  int nw = (gridDim.x * 256) >> 6;
  for (int idx = w; idx < NB * NS; idx += nw){
    double s = 0;
    #pragma unroll
    for (int i = 0; i < 6; ++i){
      float v = xin[(size_t)idx * NH + ln + 64 * i];
      s += (double)v * v;
    }
    s = wredsumd(s);
    if (ln == 0){
      double xn = normclip(s);
      double ts = (double)tst[idx];
      double xnt = sqrt(fmax(384.0 * ts * ts, 1e-15));
      float4 o;
      o.x = (float)xn;
      o.y = (float)artanh_(xn);
      o.z = (float)(artanh_(xnt) / xnt);
      o.w = (float)ts;
      *(float4*)&XNF[(size_t)idx * 4] = o;
    }
  }
}

// ---------------- chunked Q GEMM: Q[rloc][jj] = sum_c X[b(rloc)][t0+tt(rloc)][c] * UT[c][jj] ----
__global__ __launch_bounds__(256) void kqgemmc(const float* __restrict__ X,
    const float* __restrict__ Bw, float* __restrict__ Q, int t0, int CH)
{
  int j0 = blockIdx.x * 64, i0 = blockIdx.y * 64;
  __shared__ __align__(16) float As[32][68];
  __shared__ __align__(16) float Bs[32][64];
  int tid = threadIdx.x;
  int tn = tid & 15, tm = tid >> 4;
  int slm = tid >> 2;
  int slc = (tid & 3) * 8;
  int blk = tid >> 3;
  int bln = (tid & 7) * 8;
  double accd[4][4] = {{0.0}};
  int rloc = i0 + slm;
  int bb = rloc / CH, tt = rloc - bb * CH;
  const float* arow = X + ((size_t)bb * NS + t0 + tt) * NH;
  for (int c0 = 0; c0 < NH; c0 += 32){
    float4 a4 = *(const float4*)(arow + c0 + slc);
    float4 a4b = *(const float4*)(arow + c0 + slc + 4);
    As[slc+0][slm] = a4.x;  As[slc+1][slm] = a4.y;
    As[slc+2][slm] = a4.z;  As[slc+3][slm] = a4.w;
    As[slc+4][slm] = a4b.x; As[slc+5][slm] = a4b.y;
    As[slc+6][slm] = a4b.z; As[slc+7][slm] = a4b.w;
    const float* bp = Bw + (size_t)(c0 + blk) * 1536 + j0 + bln;
    float4 b4a = *(const float4*)bp;
    float4 b4b = *(const float4*)(bp + 4);
    *(float4*)&Bs[blk][bln] = b4a;
    *(float4*)&Bs[blk][bln+4] = b4b;
    __syncthreads();
    float acc[4][4] = {{0.f}};
    #pragma unroll 8
    for (int c = 0; c < 32; ++c){
      float4 av = *(const float4*)&As[c][tm*4];
      float4 bv = *(const float4*)&Bs[c][tn*4];
      float a[4] = {av.x, av.y, av.z, av.w};
      float bb2[4] = {bv.x, bv.y, bv.z, bv.w};
      #pragma unroll
      for (int mm = 0; mm < 4; ++mm)
        #pragma unroll
        for (int jj = 0; jj < 4; ++jj)
          acc[mm][jj] += a[mm] * bb2[jj];
    }
    __syncthreads();
    #pragma unroll
    for (int mm = 0; mm < 4; ++mm)
      #pragma unroll
      for (int jj = 0; jj < 4; ++jj) accd[mm][jj] += (double)acc[mm][jj];
  }
  #pragma unroll
  for (int mm = 0; mm < 4; ++mm){
    float4 o; o.x = (float)accd[mm][0]; o.y = (float)accd[mm][1];
    o.z = (float)accd[mm][2]; o.w = (float)accd[mm][3];
    *(float4*)(Q + (size_t)(i0 + tm*4 + mm) * 1536 + j0 + tn*4) = o;
  }
}

// ---------------- fp32 gate chain (sums in double, scalars in fp32) ----------------
__device__ __forceinline__ void gatef(const float* __restrict__ pg, const float* __restrict__ qg,
    float hn, float art_hn, float xn, float art_xn, float* __restrict__ out)
{
  double sp = 0, sq = 0;
  #pragma unroll
  for (int i = 0; i < 6; ++i){ sp += (double)pg[i] * pg[i]; sq += (double)qg[i] * qg[i]; }
  float pn = ncf(wredsumd(sp));
  float qn = ncf(wredsumd(sq));
  float saf = tanhf(pn / hn * art_hn) / pn;
  float sbf = tanhf(qn / xn * art_xn) / qn;
  float a6[6], b6[6]; double sx2 = 0, sy2 = 0, sxy = 0;
  #pragma unroll
  for (int i = 0; i < 6; ++i){
    a6[i] = saf * pg[i]; b6[i] = sbf * qg[i];
    sx2 += (double)a6[i] * a6[i]; sy2 += (double)b6[i] * b6[i]; sxy += (double)a6[i] * b6[i];
  }
  float x2 = (float)wredsumd(sx2);
  float y2 = (float)wredsumd(sy2);
  float xy = (float)wredsumd(sxy);
  float dd = fmaxf(1.f + 2.f * xy + x2 * y2, 1e-15f);
  float fX = (1.f + 2.f * xy + y2) / dd;
  float fY = (1.f - x2) / dd;
  float m6[6]; double smm = 0;
  #pragma unroll
  for (int i = 0; i < 6; ++i){ m6[i] = fX * a6[i] + fY * b6[i]; smm += (double)m6[i] * m6[i]; }
  float nm = ncf(wredsumd(smm));
  float slf = artanhf_(nm) / nm;
  #pragma unroll
  for (int i = 0; i < 6; ++i) out[i] = 1.f / (1.f + expf(-slf * m6[i]));
}

// ================= row-local fused recurrence: 1 row/block x 128 blocks ======================
// GEMM: all 512 threads cover NW cols once; quad-k fp8 panel: one uint4 (16B) per cq = 4 cols
//       x 4 k; HW cvt_pk_f32_fp8 decode; A fp16 in LDS (1 ds_read_b64 per cq). Panel stream
//       halved vs fp16 (the measured per-CU bottleneck). fp64 flush per 24 cq (96 c);
//       exact /4096 descale at the end.
// NL: wv0 c-path+combine; wv1-4 one gate each (wv3 = o-gate + ctx); wv5 x-prefetch (fallback).
template<int NW, int QPRE>
__global__ __launch_bounds__(512, 1) void krow(
    const unsigned* __restrict__ WTQ, const float* __restrict__ xin,
    const float* __restrict__ XNF, const float* __restrict__ Qp,
    int CH, int t0, int t1,
    float* __restrict__ ctx, float* __restrict__ HsOut,
    float* __restrict__ HSV, float* __restrict__ CCV, double* __restrict__ SCV)
{
  constexpr int NF = NW / 2048;         // uint4 per thread per cq: 1 (QPRE) or 2 (fallback)
  constexpr int D = 6;                  // prefetch depth over cq rows (max row touched 101 < 104)
  const int tid = threadIdx.x;
  const int wv = tid >> 6, ln = tid & 63;
  const int b = blockIdx.x;             // one batch row per block

  __shared__ __align__(16) float Zrow[NW];
  __shared__ __align__(8) h16 ALh[4][400];   // [slot][c]: 0=h, 1=cc, 2=x, 3=zero
  __shared__ float g384[4][384];
  __shared__ float sc[4];               // {hn, cc2, artanh(hn), pad}

  // ---- init / restore state ----
  for (int i = tid; i < 800; i += 512) ((unsigned*)ALh)[i] = 0u;
  __syncthreads();
  if (t0 > 0){
    for (int i = tid; i < 384; i += 512){
      ALh[0][i] = (h16)HSV[(size_t)b * 384 + i];
      ALh[1][i] = (h16)CCV[(size_t)b * 384 + i];
    }
  }
  if (!QPRE){
    for (int i = tid; i < 384; i += 512)
      ALh[2][i] = (h16)xin[((size_t)b * NS + t0) * NH + i];
  }
  float cc6[6], hnf = 0.f, cc2f = 0.f;
  if (wv == 0){
    if (t0 == 0){
      #pragma unroll
      for (int i = 0; i < 6; ++i) cc6[i] = 0.f;
      hnf = sqrtf(1e-15f); cc2f = 0.f;
    } else {
      #pragma unroll
      for (int i = 0; i < 6; ++i) cc6[i] = CCV[(size_t)b * 384 + ln + 64 * i];
      hnf = (float)SCV[b * 2]; cc2f = (float)SCV[b * 2 + 1];
    }
    if (ln == 0){ sc[0] = hnf; sc[1] = cc2f; sc[2] = artanhf_(hnf); }
  }
  __syncthreads();

  // column assignment (cols-once); col0 multiple of 4, all segment boundaries multiples of 4
  const int col0 = tid * (NF * 4);
  int sel;
  if (col0 < 1536) sel = 0;
  else if (col0 < 1920) sel = 1;
  else if (QPRE) sel = 3;
  else if (col0 < 2048) sel = 3;
  else if (col0 < 3584) sel = 2;
  else sel = 3;

  float qreg[6];
  float xr[6];

  for (int t = t0; t < t1; ++t){
    // ---- per-wave row scalars + prefetches (latency hidden under GEMM) ----
    float4 xf = *(const float4*)&XNF[((size_t)b * NS + t) * 4]; // {xn, art_xn, axnt, ts}
    if (QPRE){
      if (wv >= 1 && wv <= 4){
        const float* qp = Qp + ((size_t)b * CH + (t - t0)) * 1536 + (wv - 1) * 384;
        #pragma unroll
        for (int i = 0; i < 6; ++i) qreg[i] = qp[ln + 64 * i];
      }
    } else {
      if (wv == 5 && t + 1 < t1){
        #pragma unroll
        for (int i = 0; i < 6; ++i) xr[i] = xin[((size_t)b * NS + t + 1) * NH + ln + 64 * i];
      }
    }

    // ---- GEMM: cols-once, 1 row; fp8 quad panel (16B loads) + HW decode + fp32 FMA ----
    {
      const unsigned* pt[D];
      #pragma unroll
      for (int d = 0; d < D; ++d) pt[d] = WTQ + (size_t)d * NW + col0;
      uint4 wb[D][NF];
      #pragma unroll
      for (int d = 0; d < D; ++d){
        #pragma unroll
        for (int k = 0; k < NF; ++k) wb[d][k] = *(const uint4*)(pt[d] + 4 * k);
        pt[d] += (size_t)D * NW;
      }
      double ad[NF * 4];
      #pragma unroll
      for (int k = 0; k < NF * 4; ++k) ad[k] = 0.0;
      for (int g4 = 0; g4 < 96; g4 += 24){       // 24 cq = 96 c per flush group
        float acc[NF * 4];
        #pragma unroll
        for (int k = 0; k < NF * 4; ++k) acc[k] = 0.f;
        for (int cc = 0; cc < 24; cc += D){
          #pragma unroll
          for (int d = 0; d < D; ++d){
            const int cq = g4 + cc + d;
            h16x4 ap = *(const h16x4*)&ALh[sel][4 * cq];
            float a0 = (float)ap[0], a1 = (float)ap[1];
            float a2 = (float)ap[2], a3 = (float)ap[3];
            #pragma unroll
            for (int k = 0; k < NF; ++k){
              uint4 u = wb[d][k];
              unsigned uw[4] = {u.x, u.y, u.z, u.w};
              #pragma unroll
              for (int m = 0; m < 4; ++m){
                f32x2 lo = __builtin_amdgcn_cvt_pk_f32_fp8((int)uw[m], false);
                f32x2 hi = __builtin_amdgcn_cvt_pk_f32_fp8((int)uw[m], true);
                acc[4*k+m] = fmaf(lo.x, a0, acc[4*k+m]);
                acc[4*k+m] = fmaf(lo.y, a1, acc[4*k+m]);
                acc[4*k+m] = fmaf(hi.x, a2, acc[4*k+m]);
                acc[4*k+m] = fmaf(hi.y, a3, acc[4*k+m]);
              }
              wb[d][k] = *(const uint4*)(pt[d] + 4 * k);
            }
            pt[d] += (size_t)D * NW;
          }
        }
        #pragma unroll
        for (int k = 0; k < NF * 4; ++k) ad[k] += (double)acc[k];
      }
      #pragma unroll
      for (int k = 0; k < NF; ++k){
        float4 o;
        o.x = (float)(ad[4 * k + 0] * 0.000244140625);   // exact /4096
        o.y = (float)(ad[4 * k + 1] * 0.000244140625);
        o.z = (float)(ad[4 * k + 2] * 0.000244140625);
        o.w = (float)(ad[4 * k + 3] * 0.000244140625);
        *(float4*)&Zrow[col0 + 4 * k] = o;
      }
    }
    __syncthreads();   // B1: Zrow ready

    // ---- NL (fp32 scalar chain, double reduces) ----
    float hn_s = sc[0];
    float art_hn = sc[2];
    float cadj[6];
    if (wv == 0){
      float tsf = xf.w, axnt = xf.z;
      float cnf = sqrtf(fmaxf(cc2f, 1e-15f));
      float mv6[6]; double s_mv = 0;
      #pragma unroll
      for (int i = 0; i < 6; ++i){
        mv6[i] = Zrow[1536 + ln + 64 * i];
        s_mv += (double)mv6[i] * mv6[i];
      }
      float mvn = ncf(wredsumd(s_mv));
      float s1 = tanhf(mvn / cnf * artanhf_(cnf));
      float c1f = s1 / mvn;
      float m1[6]; double sm1 = 0;
      #pragma unroll
      for (int i = 0; i < 6; ++i){ m1[i] = c1f * mv6[i]; sm1 += (double)m1[i] * m1[i]; }
      float n1 = ncf(wredsumd(sm1));
      float l1f = artanhf_(n1) / n1;
      float v6[6]; double sv = 0;
      #pragma unroll
      for (int i = 0; i < 6; ++i){ v6[i] = tanhf(l1f * m1[i]); sv += (double)v6[i] * v6[i]; }
      float nv = ncf(wredsumd(sv));
      float e1f = tanhf(nv) / nv;
      float cs1[6]; double scs = 0, sccd = 0;
      #pragma unroll
      for (int i = 0; i < 6; ++i){ cs1[i] = e1f * v6[i]; scs += (double)cs1[i] * cs1[i]; sccd -= (double)cs1[i] * cc6[i]; }
      double swx = 0;
      #pragma unroll
      for (int i = 0; i < 6; ++i){ float w = cs1[i] * tsf; swx += (double)w * w; }
      float wxn1 = ncf(wredsumd(swx));
      float s2f = tanhf(wxn1 * axnt) / wxn1 * tsf;
      float cs2[6];
      #pragma unroll
      for (int i = 0; i < 6; ++i) cs2[i] = s2f * cs1[i];
      float x2a = (float)wredsumd(scs);
      float xya = (float)wredsumd(sccd);
      float y2a = cc2f;
      float dA = fmaxf(1.f + 2.f * xya + x2a * y2a, 1e-15f);
      float fXA = (1.f + 2.f * xya + y2a) / dA;
      float fYA = (1.f - x2a) / dA;
      float A6[6]; double sA = 0, sAc = 0, sc2_ = 0;
      #pragma unroll
      for (int i = 0; i < 6; ++i){
        A6[i] = fXA * (-cs1[i]) + fYA * cc6[i];
        sA += (double)A6[i] * A6[i]; sAc += (double)A6[i] * cs2[i]; sc2_ += (double)cs2[i] * cs2[i];
      }
      float x2b = (float)wredsumd(sA);
      float xyb = (float)wredsumd(sAc);
      float y2b = (float)wredsumd(sc2_);
      float dB = fmaxf(1.f + 2.f * xyb + x2b * y2b, 1e-15f);
      float fXB = (1.f + 2.f * xyb + y2b) / dB;
      float fYB = (1.f - x2b) / dB;
      #pragma unroll
      for (int i = 0; i < 6; ++i) cadj[i] = fXB * A6[i] + fYB * cs2[i];
    } else if (wv >= 1 && wv <= 4){
      const int g = wv - 1;
      float pg[6], qg[6], og[6];
      #pragma unroll
      for (int i = 0; i < 6; ++i){
        int r = ln + 64 * i;
        pg[i] = Zrow[g * 384 + r];
        qg[i] = QPRE ? qreg[i] : Zrow[2048 + g * 384 + r];
      }
      gatef(pg, qg, hn_s, art_hn, xf.x, xf.y, og);
      if (g == 2){
        #pragma unroll
        for (int i = 0; i < 6; ++i){
          int r = ln + 64 * i;
          g384[2][r] = og[i];
          ctx[((size_t)b * NS + t) * NH + r] = og[i];   // o-gate is the context
        }
      } else {
        #pragma unroll
        for (int i = 0; i < 6; ++i) g384[g][ln + 64 * i] = og[i];
      }
    }
    __syncthreads();   // B2: gates ready

    if (wv == 0){
      float g0[6], g1[6], g2[6], g3[6];
      #pragma unroll
      for (int i = 0; i < 6; ++i){
        int r = ln + 64 * i;
        g0[i] = g384[0][r]; g1[i] = g384[1][r];
        g2[i] = g384[2][r]; g3[i] = g384[3][r];
      }
      double sct = 0, sict = 0; float wP[6];
      #pragma unroll
      for (int i = 0; i < 6; ++i){ float ct = g3[i]; sct += (double)ct * ct; wP[i] = g1[i] * ct; sict += (double)wP[i] * wP[i]; }
      float ctn = ncf(wredsumd(sct));
      float wPn = ncf(wredsumd(sict));
      float sPf = tanhf(wPn / ctn * artanhf_(ctn)) / wPn;
      float P6[6]; double sPP = 0;
      #pragma unroll
      for (int i = 0; i < 6; ++i){ P6[i] = sPf * wP[i]; sPP += (double)P6[i] * P6[i]; }
      double sca = 0, sfca = 0; float wQ[6];
      #pragma unroll
      for (int i = 0; i < 6; ++i){ sca += (double)cadj[i] * cadj[i]; wQ[i] = g0[i] * cadj[i]; sfca += (double)wQ[i] * wQ[i]; }
      float can = ncf(wredsumd(sca));
      float wQn = ncf(wredsumd(sfca));
      float sQf = tanhf(wQn / can * artanhf_(can)) / wQn;
      float Q6[6]; double sQQ = 0, sPQ = 0;
      #pragma unroll
      for (int i = 0; i < 6; ++i){ Q6[i] = sQf * wQ[i]; sQQ += (double)Q6[i] * Q6[i]; sPQ += (double)P6[i] * Q6[i]; }
      float x2c = (float)wredsumd(sPP);
      float y2c = (float)wredsumd(sQQ);
      float xyc = (float)wredsumd(sPQ);
      float dC = fmaxf(1.f + 2.f * xyc + x2c * y2c, 1e-15f);
      float fXC = (1.f + 2.f * xyc + y2c) / dC;
      float fYC = (1.f - x2c) / dC;
      float ccn6[6], w6[6]; double sw_ = 0;
      #pragma unroll
      for (int i = 0; i < 6; ++i){ ccn6[i] = fXC * P6[i] + fYC * Q6[i]; w6[i] = tanhf(ccn6[i]); sw_ += (double)w6[i] * w6[i]; }
      float nw = ncf(wredsumd(sw_));
      float eef = tanhf(nw) / nw;
      float e6[6], wH[6]; double se = 0, soe = 0;
      #pragma unroll
      for (int i = 0; i < 6; ++i){ e6[i] = eef * w6[i]; se += (double)e6[i] * e6[i]; wH[i] = g2[i] * e6[i]; soe += (double)wH[i] * wH[i]; }
      float en = ncf(wredsumd(se));
      float wHn = ncf(wredsumd(soe));
      float sHf = tanhf(wHn / en * artanhf_(en)) / wHn;
      float hv[6]; double sh2 = 0, scc2 = 0;
      #pragma unroll
      for (int i = 0; i < 6; ++i){
        hv[i] = sHf * wH[i];
        sh2 += (double)hv[i] * hv[i];
        scc2 += (double)ccn6[i] * ccn6[i];
      }
      float hn_next = ncf(wredsumd(sh2));
      float cc2_next = (float)wredsumd(scc2);
      #pragma unroll
      for (int i = 0; i < 6; ++i){
        int r = ln + 64 * i;
        cc6[i] = ccn6[i];
        ALh[0][r] = (h16)hv[i];
        ALh[1][r] = (h16)ccn6[i];
      }
      hnf = hn_next; cc2f = cc2_next;
      if (ln == 0){ sc[0] = hn_next; sc[1] = cc2_next; sc[2] = artanhf_(hn_next); }
      if (t == t1 - 1){
        #pragma unroll
        for (int i = 0; i < 6; ++i){
          int r = ln + 64 * i;
          HSV[(size_t)b * 384 + r] = hv[i];
          CCV[(size_t)b * 384 + r] = ccn6[i];
        }
        if (ln == 0){ SCV[b * 2] = (double)hn_next; SCV[b * 2 + 1] = (double)cc2_next; }
      }
      if (t == NS - 1){
        #pragma unroll
        for (int i = 0; i < 6; ++i) HsOut[b * NH + ln + 64 * i] = hv[i];
      }
    }
    if (!QPRE && wv == 5 && t + 1 < t1){
      #pragma unroll
      for (int i = 0; i < 6; ++i) ALh[2][ln + 64 * i] = (h16)xr[i];
    }
    __syncthreads();   // B3: state ready for next t
  }
}

// ---------------- block reduce helpers ----------------
__device__ __forceinline__ double blocksumd(double v, double* red){
  v = wredsumd(v);
  __syncthreads();
  if ((threadIdx.x & 63) == 0) red[threadIdx.x >> 6] = v;
  __syncthreads();
  return red[0] + red[1] + red[2] + red[3];
}
__device__ __forceinline__ double blockmaxd(double v, double* red){
  #pragma unroll
  for (int off = 32; off; off >>= 1) v = fmax(v, __shfl_xor(v, off, 64));
  __syncthreads();
  if ((threadIdx.x & 63) == 0) red[threadIdx.x >> 6] = v;
  __syncthreads();
  return fmax(fmax(red[0], red[1]), fmax(red[2], red[3]));
}

// ---------------- query / scores / softmax / aw / bt ----------------
__global__ __launch_bounds__(256) void kattn1(const float* __restrict__ Hs,
    const float* __restrict__ Win, const float* __restrict__ ctx,
    const float* __restrict__ dt, const float* __restrict__ ab,
    double* __restrict__ query, double* __restrict__ aw, double* __restrict__ bt)
{
  int b = blockIdx.x; int tid = threadIdx.x;
  __shared__ double hL[NH], qL[NH], scs[NS];
  __shared__ double red[4];
  for (int r = tid; r < NH; r += 256) hL[r] = (double)Hs[b * NH + r];
  __syncthreads();
  for (int r = tid; r < NH; r += 256){
    double s = 0;
    const float* wr = Win + (size_t)r * NH;
    for (int c = 0; c < NH; ++c) s += hL[c] * (double)wr[c];
    qL[r] = s; query[b * NH + r] = s;
  }
  __syncthreads();
  int wv = tid >> 6, ln = tid & 63;
  for (int s_ = wv; s_ < NS; s_ += 4){
    const float* crow = ctx + ((size_t)b * NS + s_) * NH;
    double par = 0;
    #pragma unroll
    for (int i = 0; i < 6; ++i){ int d = ln + 64 * i; par += qL[d] * (double)crow[d]; }
    par = wredsumd(par);
    if (ln == 0) scs[s_] = par;
  }
  __syncthreads();
  double v0 = scs[tid];
  double v1 = (tid + 256 < NS) ? scs[tid + 256] : -1e300;
  double mx = blockmaxd(fmax(v0, v1), red);
  double e0 = exp(v0 - mx);
  double e1 = (tid + 256 < NS) ? exp(v1 - mx) : 0.0;
  double tot = blocksumd(e0 + e1, red);
  double a0 = e0 / tot, a1 = e1 / tot;
  double n = normclip(blocksumd(a0 * a0 + a1 * a1, red));
  double s1 = tanh(n) / n;
  double w0 = s1 * a0, w1 = s1 * a1;
  double pn = normclip(blocksumd(w0 * w0 + w1 * w1, red));
  if (pn > 0.999){ double f = 0.999 / pn; w0 *= f; w1 *= f; }
  aw[b * NS + tid] = w0;
  if (tid + 256 < NS) aw[b * NS + tid + 256] = w1;
  double abv = (double)ab[b];
  double b0 = exp(-abv * (double)dt[b * NS + tid]);
  double b1v = (tid + 256 < NS) ? exp(-abv * (double)dt[b * NS + tid + 256]) : 0.0;
  double nb = normclip(blocksumd(b0 * b0 + b1v * b1v, red));
  double sb = tanh(nb) / nb;
  double c0 = sb * b0, c1 = sb * b1v;
  double pnb = normclip(blocksumd(c0 * c0 + c1 * c1, red));
  if (pnb > 0.999){ double f = 0.999 / pnb; c0 *= f; c1 *= f; }
  bt[b * NS + tid] = c0;
  if (tid + 256 < NS) bt[b * NS + tid + 256] = c1;
}

// ---------------- hyperbolic attention mixing ----------------
__global__ __launch_bounds__(256) void kmix(const float* __restrict__ ctx,
    const double* __restrict__ aw, const double* __restrict__ bt,
    const float* __restrict__ ae, double* __restrict__ nom, double* __restrict__ den)
{
  int b = blockIdx.y; int h0 = blockIdx.x * 32;
  __shared__ float T[32][385];
  int tid = threadIdx.x;
  for (int idx = tid; idx < NS * 32; idx += 256){
    int s = idx >> 5, hh = idx & 31;
    T[hh][s] = ctx[((size_t)b * NS + s) * NH + h0 + hh];
  }
  __syncthreads();
  int wv = tid >> 6, ln = tid & 63;
  double aev = (double)ae[b];
  double aw6[6], bt6[6]; double sbt = 0;
  #pragma unroll
  for (int i = 0; i < 6; ++i){
    aw6[i] = aw[b * NS + ln + 64 * i];
    bt6[i] = bt[b * NS + ln + 64 * i];
    sbt += bt6[i] * bt6[i];
  }
  double xnb = normclip(wredsumd(sbt));
  double art_xnb = artanh_(xnb);
  double denacc = 0.0;
  for (int k = 0; k < 8; ++k){
    int hh = wv * 8 + k;
    double v[6]; double sx = 0;
    #pragma unroll
    for (int i = 0; i < 6; ++i){ v[i] = (double)T[hh][ln + 64 * i]; sx += v[i] * v[i]; }
    double xnv = normclip(wredsumd(sx));
    double wx[6]; double swx = 0;
    #pragma unroll
    for (int i = 0; i < 6; ++i){ wx[i] = aw6[i] * v[i]; swx += wx[i] * wx[i]; }
    double wxn = normclip(wredsumd(swx));
    double s1 = tanh(wxn / xnv * artanh_(xnv)) / wxn;
    double mix[6]; double sm = 0;
    #pragma unroll
    for (int i = 0; i < 6; ++i){ mix[i] = s1 * wx[i]; sm += mix[i] * mix[i]; }
    double n1 = normclip(wredsumd(sm));
    if (n1 > 0.999){ double f = 0.999 / n1;
      #pragma unroll
      for (int i = 0; i < 6; ++i) mix[i] *= f; }
    double sm2 = 0;
    #pragma unroll
    for (int i = 0; i < 6; ++i) sm2 += mix[i] * mix[i];
    double xn2 = normclip(wredsumd(sm2));
    double wx2[6]; double sw2 = 0;
    #pragma unroll
    for (int i = 0; i < 6; ++i){ wx2[i] = aev * mix[i]; sw2 += wx2[i] * wx2[i]; }
    double wxn2 = normclip(wredsumd(sw2));
    double s2 = tanh(wxn2 / xn2 * artanh_(xn2)) / wxn2;
    double tmp[6]; double st = 0;
    #pragma unroll
    for (int i = 0; i < 6; ++i){ tmp[i] = s2 * wx2[i]; st += tmp[i] * tmp[i]; }
    double n2 = normclip(wredsumd(st));
    if (n2 > 0.999){ double f = 0.999 / n2;
      #pragma unroll
      for (int i = 0; i < 6; ++i) tmp[i] *= f; }
    double wx3[6]; double sw3 = 0;
    #pragma unroll
    for (int i = 0; i < 6; ++i){ wx3[i] = tmp[i] * bt6[i]; sw3 += wx3[i] * wx3[i]; }
    double wxn3 = normclip(wredsumd(sw3));
    double s3 = tanh(wxn3 / xnb * art_xnb) / wxn3;
    double t2[6]; double st2 = 0;
    #pragma unroll
    for (int i = 0; i < 6; ++i){ t2[i] = s3 * wx3[i]; st2 += t2[i] * t2[i]; }
    double n3 = normclip(wredsumd(st2));
    if (n3 > 0.999){ double f = 0.999 / n3;
      #pragma unroll
      for (int i = 0; i < 6; ++i) t2[i] *= f; }
    #pragma unroll
    for (int i = 0; i < 6; ++i) t2[i] = fmax(t2[i], 0.0);
    double sxx = 0, syy = 0, sxy = 0;
    #pragma unroll
    for (int i = 0; i < 6; ++i){ sxx += mix[i] * mix[i]; syy += t2[i] * t2[i]; sxy += mix[i] * t2[i]; }
    sxx = wredsumd(sxx); syy = wredsumd(syy); sxy = wredsumd(sxy);
    double dn = fmax(1.0 + 2.0 * sxy + sxx * syy, 1e-15);
    double ca = (1.0 + 2.0 * sxy + syy) / dn, cb = (1.0 - sxx) / dn;
    double m2[6]; double sm3 = 0;
    #pragma unroll
    for (int i = 0; i < 6; ++i){ m2[i] = ca * mix[i] + cb * t2[i]; sm3 += m2[i] * m2[i]; }
    double n4 = normclip(wredsumd(sm3));
    if (n4 > 0.999){ double f = 0.999 / n4;
      #pragma unroll
      for (int i = 0; i < 6; ++i) m2[i] *= f; }
    double snn = 0;
    #pragma unroll
    for (int i = 0; i < 6; ++i) snn += m2[i] * m2[i];
    snn = wredsumd(snn);
    double lam = 2.0 / fmax(1.0 - snn, 1e-15);
    #pragma unroll
    for (int i = 0; i < 6; ++i) atomicAdd(&nom[b * NS + ln + 64 * i], lam * m2[i]);
    if (ln == 0) denacc += lam - 1.0;
  }
  if (ln == 0) atomicAdd(&den[b], denacc);
}

// ---------------- midpoint + logmap0 + output head ----------------
__global__ __launch_bounds__(256) void kfinal(const double* __restrict__ nom,
    const double* __restrict__ den, const double* __restrict__ query,
    const float* __restrict__ Wout, const float* __restrict__ W1,
    const float* __restrict__ b1, const float* __restrict__ W2,
    const float* __restrict__ b2, float* __restrict__ out)
{
  int b = blockIdx.x; int tid = threadIdx.x;
  __shared__ double comb[768];
  __shared__ double att[NH];
  __shared__ double x1[NH];
  __shared__ double red[4];
  double dnb = fmax(den[b], 1e-10);
  double u0 = nom[b * NS + tid] / dnb;
  double u1 = (tid + 256 < NS) ? nom[b * NS + tid + 256] / dnb : 0.0;
  double n = normclip(blocksumd(u0 * u0 + u1 * u1, red));
  double sf = tanh(0.5 * artanh_(n)) / n;
  double f0 = sf * u0, f1 = sf * u1;
  double n2 = normclip(blocksumd(f0 * f0 + f1 * f1, red));
  double sl = artanh_(n2) / n2;
  comb[tid] = sl * f0;
  if (tid + 256 < NS) comb[tid + 256] = sl * f1;
  for (int r = tid; r < NH; r += 256) comb[NH + r] = query[b * NH + r];
  __syncthreads();
  for (int r = tid; r < NH; r += 256){
    double s = 0;
    const float* wr = Wout + (size_t)r * 768;
    for (int c = 0; c < 768; ++c) s += comb[c] * (double)wr[c];
    att[r] = tanh(s);
  }
  __syncthreads();
  for (int r = tid; r < NH; r += 256){
    double s = (double)b1[r];
    const float* wr = W1 + (size_t)r * NH;
    for (int c = 0; c < NH; ++c) s += att[c] * (double)wr[c];
    x1[r] = fmax(s, 0.0);
  }
  __syncthreads();
  double p0 = 0, p1 = 0;
  for (int c = tid; c < NH; c += 256){ p0 += x1[c] * (double)W2[c]; p1 += x1[c] * (double)W2[NH + c]; }
  p0 = blocksumd(p0, red);
  p1 = blocksumd(p1, red);
  if (tid == 0){ out[b * 2 + 0] = (float)(p0 + (double)b2[0]); out[b * 2 + 1] = (float)(p1 + (double)b2[1]); }
}

extern "C" void kernel_launch(void* const* d_in, const int* in_sizes, int n_in,
                              void* d_out, int out_size, void* d_ws, size_t ws_size,
                              hipStream_t stream)
{
  (void)in_sizes; (void)n_in; (void)out_size;
  const float* inputs  = (const float*)d_in[0];
  const float* tstamps = (const float*)d_in[1];
  const float* delta_t = (const float*)d_in[2];
  const float* W_all   = (const float*)d_in[3];
  const float* U_all   = (const float*)d_in[4];
  const float* W_d     = (const float*)d_in[5];
  const float* Win     = (const float*)d_in[6];
  const float* Wout    = (const float*)d_in[7];
  const float* ae      = (const float*)d_in[8];
  const float* ab      = (const float*)d_in[9];
  const float* W1      = (const float*)d_in[10];
  const float* b1      = (const float*)d_in[11];
  const float* W2      = (const float*)d_in[12];
  const float* b2      = (const float*)d_in[13];
  float* out = (float*)d_out;

  // double region
  double* wd = (double*)d_ws;
  size_t od = 0;
  double* NOMD  = wd + od; od += (size_t)NB * NS;
  double* DEND  = wd + od; od += (size_t)NB;
  double* QUERY = wd + od; od += (size_t)NB * NH;
  double* AW    = wd + od; od += (size_t)NB * NS;
  double* BT    = wd + od; od += (size_t)NB * NS;
  double* SCV   = wd + od; od += (size_t)NB * 2;
  // float region
  float* wf = (float*)(wd + od);
  size_t of = 0;
  unsigned* WTQ = (unsigned*)(wf + of); of += (size_t)104 * 4096;  // fp8 quad panel (max layout)
  float* UT   = wf + of; of += (size_t)384 * 1536;
  float* CTX  = wf + of; of += (size_t)NB * NS * NH;
  float* HS   = wf + of; of += (size_t)NB * NH;
  float* HSV  = wf + of; of += (size_t)NB * NH;        // chunk-boundary h state
  float* CCV  = wf + of; of += (size_t)NB * NH;        // chunk-boundary cc state
  float* XNF  = wf + of; of += (size_t)NB * NS * 4;    // {xn, art_xn, axnt, ts}
  float* Qp   = wf + of;                               // Qp chunk buffer (sized by CH)

  size_t base_bytes = od * 8 + of * 4;

  // pick the largest time-chunk whose Qp buffer fits the workspace
  int CH = 0;
  const int chs[7] = {384, 192, 96, 48, 24, 12, 6};
  for (int ci = 0; ci < 7; ++ci){
    size_t need = base_bytes + (size_t)NB * chs[ci] * 1536 * 4;
    if (ws_size >= need){ CH = chs[ci]; break; }
  }

  // zero midpoint accumulators + per-(b,t) scalar precompute
  int nzd = NB * NS + NB;
  hipLaunchKernelGGL(kzerod, dim3((nzd + 255) / 256), dim3(256), 0, stream, NOMD, nzd);
  hipLaunchKernelGGL(kxn, dim3(768), dim3(256), 0, stream, inputs, tstamps, XNF);

  if (CH > 0){
    // fp8 quad panel, 1920 useful cols (0.74 MB, L2-resident per XCD)
    int nWQ = 104 * 2048;
    hipLaunchKernelGGL(kprepWQ, dim3((nWQ + 255) / 256), dim3(256), 0, stream,
                       W_all, W_d, U_all, WTQ, 2048);
    hipLaunchKernelGGL(kprepU, dim3((384 * 1536 + 255) / 256), dim3(256), 0, stream, U_all, UT);
    for (int t0 = 0; t0 < NS; t0 += CH){
      hipLaunchKernelGGL(kqgemmc, dim3(24, 2 * CH), dim3(256), 0, stream,
                         inputs, UT, Qp, t0, CH);
      hipLaunchKernelGGL(HIP_KERNEL_NAME(krow<2048, 1>), dim3(128), dim3(512), 0, stream,
                         WTQ, inputs, XNF, Qp, CH, t0, t0 + CH,
                         CTX, HS, HSV, CCV, SCV);
    }
  } else {
    // workspace too small even for CH=6: single-launch fallback (U columns in-panel)
    int nWQ = 104 * 4096;
    hipLaunchKernelGGL(kprepWQ, dim3((nWQ + 255) / 256), dim3(256), 0, stream,
                       W_all, W_d, U_all, WTQ, 4096);
    hipLaunchKernelGGL(HIP_KERNEL_NAME(krow<4096, 0>), dim3(128), dim3(512), 0, stream,
                       WTQ, inputs, XNF, Qp /*unused*/, 1, 0, NS,
                       CTX, HS, HSV, CCV, SCV);
  }

  hipLaunchKernelGGL(kattn1, dim3(128), dim3(256), 0, stream,
                     HS, Win, CTX, delta_t, ab, QUERY, AW, BT);
  hipLaunchKernelGGL(kmix, dim3(12, 128), dim3(256), 0, stream, CTX, AW, BT, ae, NOMD, DEND);
  hipLaunchKernelGGL(kfinal, dim3(128), dim3(256), 0, stream,
                     NOMD, DEND, QUERY, Wout, W1, b1, W2, b2, out);
}